// Round 9
// baseline (1176.151 us; speedup 1.0000x reference)
//
#include <hip/hip_runtime.h>
#include <math.h>

#define Bsz  4
#define Tlen 2048
#define Dm   1024
#define Hh   8
#define dh   128
#define Mrows (Bsz * Tlen)   // 8192
#define CH   128             // checkpoint interval for pass 2
#define NCH  (Tlen / CH)     // 16 checkpoint chunks
#define C64  64              // solve chunk
#define NC64 (Tlen / C64)    // 32 solve chunks

typedef __attribute__((ext_vector_type(8))) short  s16x8;
typedef __attribute__((ext_vector_type(4))) float  f32x4;

__device__ inline unsigned short f2b_rne(float f) {
    unsigned int u = __float_as_uint(f);
    u += 0x7FFFu + ((u >> 16) & 1u);
    return (unsigned short)(u >> 16);
}
__device__ inline float b2f(unsigned short u) {
    return __uint_as_float(((unsigned int)u) << 16);
}

__global__ __launch_bounds__(256) void cvt_f32_bf16(const float* __restrict__ in,
                                                    unsigned short* __restrict__ out)
{
    const size_t i = ((size_t)blockIdx.x * 256 + threadIdx.x) * 4;
    float4 v = *(const float4*)&in[i];
    ushort4 o;
    o.x = f2b_rne(v.x); o.y = f2b_rne(v.y);
    o.z = f2b_rne(v.z); o.w = f2b_rne(v.w);
    *(ushort4*)&out[i] = o;
}

// ---------------------------------------------------------------------------
// bf16 MFMA GEMM: val = sum_k A[m][k]*W[n][k] (+bias)   (unchanged, proven)
// ---------------------------------------------------------------------------
__global__ __launch_bounds__(256) void gemm_bf16(const unsigned short* __restrict__ A,
                                                 const unsigned short* __restrict__ Wt,
                                                 const float* __restrict__ bias,
                                                 float* __restrict__ Yf,
                                                 unsigned short* __restrict__ Y16,
                                                 int mode)
{
    __shared__ __align__(16) unsigned short As[128 * 32];
    __shared__ __align__(16) unsigned short Bs[128 * 32];

    const int tid   = threadIdx.x;
    const int w     = tid >> 6;
    const int lane  = tid & 63;
    const int r4    = lane >> 2;
    const int p4    = lane & 3;
    const int row16 = lane & 15;
    const int quad  = lane >> 4;

    const int m0 = blockIdx.y * 128;
    const int n0 = blockIdx.x * 128;
    const int wm = (w >> 1) * 64;
    const int wn = (w & 1) * 64;

    f32x4 acc[4][4];
#pragma unroll
    for (int i = 0; i < 4; ++i)
#pragma unroll
        for (int j = 0; j < 4; ++j)
            acc[i][j] = (f32x4){0.f, 0.f, 0.f, 0.f};

    for (int k0 = 0; k0 < 1024; k0 += 32) {
        __syncthreads();
#pragma unroll
        for (int c = 0; c < 2; ++c) {
            const int ml  = w * 32 + c * 16 + r4;
            const int swz = (ml >> 1) & 3;
            const unsigned short* ga = A  + (size_t)(m0 + ml) * 1024 + k0 + ((p4 ^ swz) << 3);
            const unsigned short* gb = Wt + (size_t)(n0 + ml) * 1024 + k0 + ((p4 ^ swz) << 3);
            __builtin_amdgcn_global_load_lds(
                (const __attribute__((address_space(1))) void*)ga,
                (__attribute__((address_space(3))) void*)&As[(w * 32 + c * 16) * 32], 16, 0, 0);
            __builtin_amdgcn_global_load_lds(
                (const __attribute__((address_space(1))) void*)gb,
                (__attribute__((address_space(3))) void*)&Bs[(w * 32 + c * 16) * 32], 16, 0, 0);
        }
        __syncthreads();

        s16x8 af[4], bf[4];
#pragma unroll
        for (int bm = 0; bm < 4; ++bm) {
            const int ml  = wm + bm * 16 + row16;
            const int pos = quad ^ ((ml >> 1) & 3);
            af[bm] = *(const s16x8*)&As[ml * 32 + pos * 8];
        }
#pragma unroll
        for (int bn = 0; bn < 4; ++bn) {
            const int nl  = wn + bn * 16 + row16;
            const int pos = quad ^ ((nl >> 1) & 3);
            bf[bn] = *(const s16x8*)&Bs[nl * 32 + pos * 8];
        }
#pragma unroll
        for (int bm = 0; bm < 4; ++bm)
#pragma unroll
            for (int bn = 0; bn < 4; ++bn)
                acc[bm][bn] = __builtin_amdgcn_mfma_f32_16x16x32_bf16(af[bm], bf[bn], acc[bm][bn], 0, 0, 0);
    }

#pragma unroll
    for (int bm = 0; bm < 4; ++bm) {
        const int row = m0 + wm + bm * 16 + quad * 4;
#pragma unroll
        for (int bn = 0; bn < 4; ++bn) {
            const int col = n0 + wn + bn * 16 + row16;
            const float bb = bias ? bias[col] : 0.f;
#pragma unroll
            for (int r = 0; r < 4; ++r) {
                float val = acc[bm][bn][r] + bb;
                if (mode == 1) val = 1.f / (1.f + __expf(-val));
                if (mode == 2) Y16[(size_t)(row + r) * 1024 + col] = f2b_rne(val);
                else           Yf [(size_t)(row + r) * 1024 + col] = val;
            }
        }
    }
}

// ---------------------------------------------------------------------------
// L2-normalize K,V rows in place; write normalized K as bf16 (K16) and the
// bf16 residual (K16lo) for precision-compensated Grams.
// ---------------------------------------------------------------------------
__global__ __launch_bounds__(256) void l2norm_rows(float* __restrict__ Kb,
                                                   float* __restrict__ Vb,
                                                   unsigned short* __restrict__ K16,
                                                   unsigned short* __restrict__ K16lo)
{
    const int gtid = blockIdx.x * 256 + threadIdx.x;
    const int row  = gtid >> 6;
    const int lane = threadIdx.x & 63;
    const size_t base = (size_t)row * dh + lane * 2;

    float2 k2 = *(float2*)&Kb[base];
    float2 v2 = *(float2*)&Vb[base];
    float sk = k2.x * k2.x + k2.y * k2.y;
    float sv = v2.x * v2.x + v2.y * v2.y;
#pragma unroll
    for (int off = 1; off < 64; off <<= 1) {
        sk += __shfl_xor(sk, off);
        sv += __shfl_xor(sv, off);
    }
    const float rk = 1.f / fmaxf(sqrtf(sk), 1e-12f);
    const float rv = 1.f / fmaxf(sqrtf(sv), 1e-12f);
    k2.x *= rk; k2.y *= rk;
    v2.x *= rv; v2.y *= rv;
    *(float2*)&Kb[base] = k2;
    *(float2*)&Vb[base] = v2;
    const unsigned short hx = f2b_rne(k2.x), hy = f2b_rne(k2.y);
    ((unsigned int*)K16)[base >> 1] = (unsigned int)hx | ((unsigned int)hy << 16);
    const unsigned short lx = f2b_rne(k2.x - b2f(hx));
    const unsigned short ly = f2b_rne(k2.y - b2f(hy));
    ((unsigned int*)K16lo)[base >> 1] = (unsigned int)lx | ((unsigned int)ly << 16);
}

// ---------------------------------------------------------------------------
// gram_kt: per (bh, c64-chunk): G = K_c K_c^T (f32, lo-compensated, MFMA) and
// K^T tiles (bf16 hi/lo).  Grid: 1024 blocks, 256 threads. (unchanged)
// ---------------------------------------------------------------------------
__global__ __launch_bounds__(256) void gram_kt(const unsigned short* __restrict__ K16,
                                               const unsigned short* __restrict__ K16lo,
                                               float* __restrict__ Gf,
                                               unsigned short* __restrict__ KThi,
                                               unsigned short* __restrict__ KTlo)
{
    __shared__ __align__(16) unsigned short Kp[2][64 * 136];   // [hi/lo][t][j] pad-136

    const int blk = blockIdx.x;
    const int c   = blk & 31;
    const int bh  = blk >> 5;
    const int b   = bh >> 3, h = bh & 7;
    const int tid = threadIdx.x;

    {
        const int row = tid >> 2, seg = (tid & 3) * 32;
        const size_t gsrc = ((size_t)(b * Tlen + c * C64 + row)) * Dm + h * dh + seg;
        const s16x8* ph = (const s16x8*)&K16[gsrc];
        const s16x8* pl = (const s16x8*)&K16lo[gsrc];
#pragma unroll
        for (int q = 0; q < 4; ++q) {
            *(s16x8*)&Kp[0][row * 136 + seg + q * 8] = ph[q];
            *(s16x8*)&Kp[1][row * 136 + seg + q * 8] = pl[q];
        }
    }
    __syncthreads();

    const int w     = tid >> 6;
    const int lane  = tid & 63;
    const int row16 = lane & 15;
    const int quad  = lane >> 4;
    const int sh = (w >> 1) * 32;
    const int th = (w & 1) * 32;

    f32x4 ag[2][2];
#pragma unroll
    for (int i = 0; i < 2; ++i)
#pragma unroll
        for (int j = 0; j < 2; ++j)
            ag[i][j] = (f32x4){0.f, 0.f, 0.f, 0.f};

#pragma unroll
    for (int pass = 0; pass < 3; ++pass) {
        const int pa = (pass == 2) ? 1 : 0;
        const int pb = (pass == 1) ? 1 : 0;
#pragma unroll
        for (int k0 = 0; k0 < 128; k0 += 32) {
            s16x8 af[2], bf[2];
#pragma unroll
            for (int bm = 0; bm < 2; ++bm) {
                const int ml = sh + bm * 16 + row16;
                af[bm] = *(const s16x8*)&Kp[pa][ml * 136 + k0 + quad * 8];
            }
#pragma unroll
            for (int bn = 0; bn < 2; ++bn) {
                const int nl = th + bn * 16 + row16;
                bf[bn] = *(const s16x8*)&Kp[pb][nl * 136 + k0 + quad * 8];
            }
#pragma unroll
            for (int bm = 0; bm < 2; ++bm)
#pragma unroll
                for (int bn = 0; bn < 2; ++bn)
                    ag[bm][bn] = __builtin_amdgcn_mfma_f32_16x16x32_bf16(af[bm], bf[bn], ag[bm][bn], 0, 0, 0);
        }
    }

    float* gout = Gf + ((size_t)(bh * 32 + c)) * 4096;
#pragma unroll
    for (int bm = 0; bm < 2; ++bm)
#pragma unroll
        for (int bn = 0; bn < 2; ++bn) {
            const int t = th + bn * 16 + row16;
#pragma unroll
            for (int r = 0; r < 4; ++r) {
                const int s = sh + bm * 16 + quad * 4 + r;
                gout[s * 64 + t] = ag[bm][bn][r];
            }
        }

    {
        const int j   = tid >> 1;
        const int th2 = (tid & 1) * 32;
        unsigned int pk[16];
#pragma unroll
        for (int hl = 0; hl < 2; ++hl) {
#pragma unroll
            for (int p = 0; p < 16; ++p) {
                const unsigned short e0 = Kp[hl][(th2 + 2 * p) * 136 + j];
                const unsigned short e1 = Kp[hl][(th2 + 2 * p + 1) * 136 + j];
                pk[p] = (unsigned int)e0 | ((unsigned int)e1 << 16);
            }
            unsigned short* dst = (hl ? KTlo : KThi) +
                ((size_t)(bh * 32 + c) * 128 + j) * 64 + th2;
#pragma unroll
            for (int q = 0; q < 4; ++q)
                *(uint4*)&dst[q * 8] = *(uint4*)&pk[q * 4];
        }
    }
}

// ---------------------------------------------------------------------------
// solve_coef R9: 512 threads (8 waves), __launch_bounds__(512, 2) so the
// allocator may use up to 256 VGPRs (R8's dynamic-LDS heuristic capped at 128
// -> r4[] spilled to scratch, WRITE_SIZE +11MB, 2.4x regression).  Solver
// path trimmed: Ut stored per-group (no allphi batching).  Otherwise R8:
// 4 barriers/chunk, double-buffered K/G prefetch, A0 in own buffer,
// Wcp direct-from-registers.  Dynamic LDS: 144 KiB.
// ---------------------------------------------------------------------------
__global__ __launch_bounds__(512, 2) void solve_coef(const unsigned short* __restrict__ K16,
                                                     const float* __restrict__ Vb,
                                                     const float* __restrict__ LRb,
                                                     const float* __restrict__ Gf,
                                                     const unsigned short* __restrict__ KThi,
                                                     const unsigned short* __restrict__ KTlo,
                                                     unsigned short* __restrict__ Ut,
                                                     unsigned short* __restrict__ Wcp)
{
    extern __shared__ __align__(16) char smem[];
    unsigned short* Khs[2];                                    // 2 x 16K K staging
    Khs[0] = (unsigned short*)smem;
    Khs[1] = (unsigned short*)(smem + 16384);
    unsigned short* Ws  = (unsigned short*)(smem + 32768);     // 32K: P0/P1 W slabs; P2/P3 KT slabs
    float* Gs[2];                                              // 2 x 16K [64][64] f32
    Gs[0] = (float*)(smem + 65536);
    Gs[1] = (float*)(smem + 81920);
    unsigned short* As0 = (unsigned short*)(smem + 98304);     // 16K A0 [64 t][128 i] XOR
    unsigned short* Uhi = (unsigned short*)(smem + 114688);    // 16K [128][64] XOR
    unsigned short* Ulo = (unsigned short*)(smem + 131072);    // 16K [128][64] XOR

    const int bh = blockIdx.x;
    const int b  = bh >> 3, h = bh & 7;
    const int tid   = threadIdx.x;
    const int w     = tid >> 6;           // 0..7
    const int lane  = tid & 63;
    const int p4    = lane & 3;
    const int row16 = lane & 15;
    const int quad  = lane >> 4;
    const int wm  = (w >> 1) * 32;        // W/A0 i-quarter (0,32,64,96)
    const int wn  = (w & 1) * 64;         // W j-half
    const int th2 = (w & 1) * 32;         // A0 t-half

    f32x4 Wa[2][4];
#pragma unroll
    for (int i = 0; i < 2; ++i)
#pragma unroll
        for (int j = 0; j < 4; ++j)
            Wa[i][j] = (f32x4){0.f, 0.f, 0.f, 0.f};

    const int ilane = w * 64 + lane;      // solve row (waves 0,1)

    // ---- prologue: stage K(0) -> Khs[0], G(0) -> Gs[0] ----
    if (w == 5) {
#pragma unroll
        for (int sl = 0; sl < 4; ++sl)
#pragma unroll
            for (int c4 = 0; c4 < 4; ++c4) {
                const int rr = c4 * 16 + (lane >> 2);
                const unsigned short* ga = K16 + ((size_t)(b * Tlen + rr)) * Dm + h * dh
                                           + sl * 32 + ((p4 ^ ((rr >> 1) & 3)) << 3);
                __builtin_amdgcn_global_load_lds(
                    (const __attribute__((address_space(1))) void*)ga,
                    (__attribute__((address_space(3))) void*)((char*)Khs[0] + sl * 4096 + c4 * 1024 + lane * 16),
                    16, 0, 0);
            }
    }
    if (w == 4 || w == 6) {
        const size_t gbase = (size_t)(bh * 32 + 0) * 4096;
        const int half = (w == 6) ? 8 : 0;
#pragma unroll
        for (int c4 = 0; c4 < 8; ++c4) {
            const int seg = half + c4;
            const float* gg = Gf + gbase + seg * 256 + lane * 4;
            __builtin_amdgcn_global_load_lds(
                (const __attribute__((address_space(1))) void*)gg,
                (__attribute__((address_space(3))) void*)((char*)Gs[0] + (seg * 256 + lane * 4) * 4),
                16, 0, 0);
        }
    }
    __syncthreads();

#pragma unroll 1
    for (int c = 0; c < NC64; ++c) {
        const int t0g = c * C64;
        const int cur = c & 1;

        // ---- P0: dump W -> Ws (bf16); Wcp direct store every 2nd chunk --
#pragma unroll
        for (int bm = 0; bm < 2; ++bm)
#pragma unroll
            for (int bn = 0; bn < 4; ++bn) {
                const int j  = wn + bn * 16 + row16;
                const int sl = j >> 5, jj = j & 31;
#pragma unroll
                for (int r = 0; r < 4; ++r) {
                    const int i = wm + bm * 16 + quad * 4 + r;
                    const unsigned short hv = f2b_rne(Wa[bm][bn][r]);
                    Ws[sl * 4096 + i * 32 + (((jj >> 3) ^ ((i >> 1) & 3)) << 3) + (j & 7)] = hv;
                    if ((c & 1) == 0)
                        Wcp[((size_t)(bh * NCH + (c >> 1)) * 128 + i) * 128 + j] = hv;
                }
            }
        __syncthreads();

        // ---- P1: A0 = W * K_c^T (MFMA, 8 waves) -> As0 ------------------
        {
            f32x4 aA[2][2];
#pragma unroll
            for (int i = 0; i < 2; ++i)
#pragma unroll
                for (int j = 0; j < 2; ++j)
                    aA[i][j] = (f32x4){0.f, 0.f, 0.f, 0.f};
#pragma unroll
            for (int k0s = 0; k0s < 4; ++k0s) {
                s16x8 af[2], bf[2];
#pragma unroll
                for (int bm = 0; bm < 2; ++bm) {
                    const int ml = wm + bm * 16 + row16;
                    af[bm] = *(const s16x8*)&Ws[k0s * 4096 + ml * 32 + ((quad ^ ((ml >> 1) & 3)) << 3)];
                }
#pragma unroll
                for (int bn = 0; bn < 2; ++bn) {
                    const int nl = th2 + bn * 16 + row16;
                    bf[bn] = *(const s16x8*)&Khs[cur][k0s * 2048 + nl * 32 + ((quad ^ ((nl >> 1) & 3)) << 3)];
                }
#pragma unroll
                for (int bm = 0; bm < 2; ++bm)
#pragma unroll
                    for (int bn = 0; bn < 2; ++bn)
                        aA[bm][bn] = __builtin_amdgcn_mfma_f32_16x16x32_bf16(af[bm], bf[bn], aA[bm][bn], 0, 0, 0);
            }
#pragma unroll
            for (int bm = 0; bm < 2; ++bm)
#pragma unroll
                for (int bn = 0; bn < 2; ++bn) {
                    const int t = th2 + bn * 16 + row16;
#pragma unroll
                    for (int r = 0; r < 4; ++r) {
                        const int i = wm + bm * 16 + quad * 4 + r;
                        As0[t * 128 + (((i >> 3) ^ (t & 7)) << 3) + (i & 7)] = f2b_rne(aA[bm][bn][r]);
                    }
                }
        }
        __syncthreads();

        // ---- P2: waves 0,1 solve; 2,3 KT stage; 4,6 G-next; 5 K-next ----
        if (w == 2 || w == 3) {
            const int base2 = (w - 2) * 2;
#pragma unroll
            for (int bb = 0; bb < 2; ++bb) {
                const int buf = base2 + bb;
                const int st  = buf & 1;
                const unsigned short* src = (buf < 2) ? KThi : KTlo;
#pragma unroll
                for (int c8 = 0; c8 < 8; ++c8) {
                    const int jj = c8 * 16 + (lane >> 2);
                    const unsigned short* ga = src + ((size_t)(bh * 32 + c) * 128 + jj) * 64
                                               + st * 32 + ((p4 ^ ((jj >> 1) & 3)) << 3);
                    __builtin_amdgcn_global_load_lds(
                        (const __attribute__((address_space(1))) void*)ga,
                        (__attribute__((address_space(3))) void*)((char*)Ws + buf * 8192 + c8 * 1024 + lane * 16),
                        16, 0, 0);
                }
            }
        } else if (w == 5) {
            if (c + 1 < NC64) {
#pragma unroll
                for (int sl = 0; sl < 4; ++sl)
#pragma unroll
                    for (int c4 = 0; c4 < 4; ++c4) {
                        const int rr = c4 * 16 + (lane >> 2);
                        const unsigned short* ga = K16 + ((size_t)(b * Tlen + t0g + C64 + rr)) * Dm + h * dh
                                                   + sl * 32 + ((p4 ^ ((rr >> 1) & 3)) << 3);
                        __builtin_amdgcn_global_load_lds(
                            (const __attribute__((address_space(1))) void*)ga,
                            (__attribute__((address_space(3))) void*)((char*)Khs[cur ^ 1] + sl * 4096 + c4 * 1024 + lane * 16),
                            16, 0, 0);
                    }
            }
        } else if (w == 4 || w == 6) {
            if (c + 1 < NC64) {
                const size_t gbase = (size_t)(bh * 32 + c + 1) * 4096;
                const int half = (w == 6) ? 8 : 0;
#pragma unroll
                for (int c4 = 0; c4 < 8; ++c4) {
                    const int seg = half + c4;
                    const float* gg = Gf + gbase + seg * 256 + lane * 4;
                    __builtin_amdgcn_global_load_lds(
                        (const __attribute__((address_space(1))) void*)gg,
                        (__attribute__((address_space(3))) void*)((char*)Gs[cur ^ 1] + (seg * 256 + lane * 4) * 4),
                        16, 0, 0);
                }
            }
        } else if (w < 2) {
            const int i = ilane;
            const float* vp  = Vb  + ((size_t)(b * Tlen + t0g)) * Dm + h * dh + i;
            const float* lrp = LRb + ((size_t)(b * Tlen + t0g)) * Dm + h * dh + i;
            const float* gs  = Gs[cur];
            unsigned short* utrow = Ut + (size_t)(bh * 128 + i) * Tlen + t0g;
            // r-init: r4[q][e] = v[t] - A0[t][i],  t = 4q+e
            f32x4 r4[16];
#pragma unroll
            for (int q = 0; q < 16; ++q) {
#pragma unroll
                for (int e = 0; e < 4; ++e) {
                    const int t = 4 * q + e;
                    const float a0 = b2f(As0[t * 128 + (((i >> 3) ^ (t & 7)) << 3) + (i & 7)]);
                    r4[q][e] = vp[(size_t)t * Dm] - a0;
                }
            }
            float lv[8], o8[8];
#pragma unroll
            for (int g = 0; g < 8; ++g) {
#pragma unroll
                for (int u = 0; u < 8; ++u)
                    lv[u] = lrp[(size_t)(g * 8 + u) * Dm];
#pragma unroll
                for (int su = 0; su < 8; ++su) {
                    const int s = g * 8 + su;
                    const float cf = lv[su] * r4[s >> 2][s & 3];
                    o8[su] = cf;
                    const f32x4 cf4 = (f32x4){cf, cf, cf, cf};
#pragma unroll
                    for (int q = 2 * g; q < 16; ++q) {
                        const f32x4 g4 = *(const f32x4*)&gs[s * 64 + q * 4];
                        r4[q] -= cf4 * g4;
                    }
                }
                // pack & store U for this group (t0 = 8g) — per-group stores
                unsigned int phi[4], plo[4];
#pragma unroll
                for (int qq = 0; qq < 4; ++qq) {
                    const unsigned short h0 = f2b_rne(o8[2 * qq]);
                    const unsigned short h1 = f2b_rne(o8[2 * qq + 1]);
                    const unsigned short l0 = f2b_rne(o8[2 * qq] - b2f(h0));
                    const unsigned short l1 = f2b_rne(o8[2 * qq + 1] - b2f(h1));
                    phi[qq] = (unsigned int)h0 | ((unsigned int)h1 << 16);
                    plo[qq] = (unsigned int)l0 | ((unsigned int)l1 << 16);
                }
                const int lg = g ^ (i & 7);
                *(uint4*)&Uhi[i * 64 + (lg << 3)] = *(uint4*)phi;
                *(uint4*)&Ulo[i * 64 + (lg << 3)] = *(uint4*)plo;
                *(uint4*)&utrow[8 * g] = *(uint4*)phi;
            }
        }
        __syncthreads();

        // ---- P3: W += Uhi*KThi + Ulo*KThi + Uhi*KTlo (MFMA, 8 waves) ----
#pragma unroll
        for (int pass = 0; pass < 3; ++pass) {
            const unsigned short* Ua = (pass == 1) ? Ulo : Uhi;
            const int bufbase = (pass == 2) ? 2 : 0;
#pragma unroll
            for (int st = 0; st < 2; ++st) {
                s16x8 af[2], bf[4];
#pragma unroll
                for (int bm = 0; bm < 2; ++bm) {
                    const int ml = wm + bm * 16 + row16;
                    af[bm] = *(const s16x8*)&Ua[ml * 64 + (((st * 4 + quad) ^ (ml & 7)) << 3)];
                }
#pragma unroll
                for (int bn = 0; bn < 4; ++bn) {
                    const int nl = wn + bn * 16 + row16;
                    bf[bn] = *(const s16x8*)&Ws[(bufbase + st) * 4096 + nl * 32 + ((quad ^ ((nl >> 1) & 3)) << 3)];
                }
#pragma unroll
                for (int bm = 0; bm < 2; ++bm)
#pragma unroll
                    for (int bn = 0; bn < 4; ++bn)
                        Wa[bm][bn] = __builtin_amdgcn_mfma_f32_16x16x32_bf16(af[bm], bf[bn], Wa[bm][bn], 0, 0, 0);
            }
        }
        __syncthreads();
    }
}

// ---------------------------------------------------------------------------
// Pass 2: per 128-chunk output via MFMA.  (unchanged, proven)
// ---------------------------------------------------------------------------
__global__ __launch_bounds__(256) void chunk_o(const unsigned short* __restrict__ Q16,
                                               const unsigned short* __restrict__ K16,
                                               const unsigned short* __restrict__ Ut,
                                               const unsigned short* __restrict__ Wcp,
                                               unsigned short* __restrict__ Obb)
{
    __shared__ __align__(16) unsigned short As[128 * 32];
    __shared__ __align__(16) unsigned short Bs[128 * 32];
    __shared__ __align__(16) unsigned short Sb[128 * 136];   // +8 pad

    const int blk = blockIdx.x;
    const int c   = blk & (NCH - 1);
    const int bh  = blk >> 4;
    const int b   = bh >> 3, h = bh & 7;

    const int tid   = threadIdx.x;
    const int w     = tid >> 6;
    const int lane  = tid & 63;
    const int r4    = lane >> 2;
    const int p4    = lane & 3;
    const int row16 = lane & 15;
    const int quad  = lane >> 4;
    const int wm = (w >> 1) * 64;
    const int wn = (w & 1) * 64;

    const size_t qkbase = (size_t)b * Tlen * Dm + (size_t)(c * CH) * Dm + (size_t)h * dh;
    const size_t ubase  = (size_t)bh * dh * Tlen + (size_t)c * CH;
    const size_t wbase  = ((size_t)bh * NCH + c) * dh * dh;

    f32x4 acc[4][4];
#pragma unroll
    for (int i = 0; i < 4; ++i)
#pragma unroll
        for (int j = 0; j < 4; ++j)
            acc[i][j] = (f32x4){0.f, 0.f, 0.f, 0.f};

    for (int k0 = 0; k0 < 128; k0 += 32) {
        __syncthreads();
#pragma unroll
        for (int cc = 0; cc < 2; ++cc) {
            const int ml  = w * 32 + cc * 16 + r4;
            const int swz = (ml >> 1) & 3;
            const unsigned short* ga = Q16 + qkbase + (size_t)ml * Dm + k0 + ((p4 ^ swz) << 3);
            const unsigned short* gb = K16 + qkbase + (size_t)ml * Dm + k0 + ((p4 ^ swz) << 3);
            __builtin_amdgcn_global_load_lds(
                (const __attribute__((address_space(1))) void*)ga,
                (__attribute__((address_space(3))) void*)&As[(w * 32 + cc * 16) * 32], 16, 0, 0);
            __builtin_amdgcn_global_load_lds(
                (const __attribute__((address_space(1))) void*)gb,
                (__attribute__((address_space(3))) void*)&Bs[(w * 32 + cc * 16) * 32], 16, 0, 0);
        }
        __syncthreads();

        s16x8 af[4], bf[4];
#pragma unroll
        for (int bm = 0; bm < 4; ++bm) {
            const int ml  = wm + bm * 16 + row16;
            const int pos = quad ^ ((ml >> 1) & 3);
            af[bm] = *(const s16x8*)&As[ml * 32 + pos * 8];
        }
#pragma unroll
        for (int bn = 0; bn < 4; ++bn) {
            const int nl  = wn + bn * 16 + row16;
            const int pos = quad ^ ((nl >> 1) & 3);
            bf[bn] = *(const s16x8*)&Bs[nl * 32 + pos * 8];
        }
#pragma unroll
        for (int bm = 0; bm < 4; ++bm)
#pragma unroll
            for (int bn = 0; bn < 4; ++bn)
                acc[bm][bn] = __builtin_amdgcn_mfma_f32_16x16x32_bf16(af[bm], bf[bn], acc[bm][bn], 0, 0, 0);
    }

#pragma unroll
    for (int bm = 0; bm < 4; ++bm) {
#pragma unroll
        for (int bn = 0; bn < 4; ++bn) {
            const int s_loc = wn + bn * 16 + row16;
#pragma unroll
            for (int r = 0; r < 4; ++r) {
                const int t_loc = wm + bm * 16 + quad * 4 + r;
                const float val = (s_loc <= t_loc) ? acc[bm][bn][r] : 0.f;
                Sb[t_loc * 136 + s_loc] = f2b_rne(val);
            }
            acc[bm][bn] = (f32x4){0.f, 0.f, 0.f, 0.f};
        }
    }

    for (int k0 = 0; k0 < 128; k0 += 32) {
        __syncthreads();
#pragma unroll
        for (int cc = 0; cc < 2; ++cc) {
            const int nl  = w * 32 + cc * 16 + r4;
            const int swz = (nl >> 1) & 3;
            const unsigned short* gb = Ut + ubase + (size_t)nl * Tlen + k0 + ((p4 ^ swz) << 3);
            __builtin_amdgcn_global_load_lds(
                (const __attribute__((address_space(1))) void*)gb,
                (__attribute__((address_space(3))) void*)&Bs[(w * 32 + cc * 16) * 32], 16, 0, 0);
        }
        __syncthreads();

        s16x8 af[4], bf[4];
#pragma unroll
        for (int bm = 0; bm < 4; ++bm) {
            const int ml = wm + bm * 16 + row16;
            af[bm] = *(const s16x8*)&Sb[ml * 136 + k0 + quad * 8];
        }
#pragma unroll
        for (int bn = 0; bn < 4; ++bn) {
            const int nl  = wn + bn * 16 + row16;
            const int pos = quad ^ ((nl >> 1) & 3);
            bf[bn] = *(const s16x8*)&Bs[nl * 32 + pos * 8];
        }
#pragma unroll
        for (int bm = 0; bm < 4; ++bm)
#pragma unroll
            for (int bn = 0; bn < 4; ++bn)
                acc[bm][bn] = __builtin_amdgcn_mfma_f32_16x16x32_bf16(af[bm], bf[bn], acc[bm][bn], 0, 0, 0);
    }

    for (int k0 = 0; k0 < 128; k0 += 32) {
        __syncthreads();
#pragma unroll
        for (int cc = 0; cc < 2; ++cc) {
            const int ml  = w * 32 + cc * 16 + r4;
            const int swz = (ml >> 1) & 3;
            const unsigned short* ga = Q16 + qkbase + (size_t)ml * Dm + k0 + ((p4 ^ swz) << 3);
            const unsigned short* gb = Wcp + wbase + (size_t)ml * dh + k0 + ((p4 ^ swz) << 3);
            __builtin_amdgcn_global_load_lds(
                (const __attribute__((address_space(1))) void*)ga,
                (__attribute__((address_space(3))) void*)&As[(w * 32 + cc * 16) * 32], 16, 0, 0);
            __builtin_amdgcn_global_load_lds(
                (const __attribute__((address_space(1))) void*)gb,
                (__attribute__((address_space(3))) void*)&Bs[(w * 32 + cc * 16) * 32], 16, 0, 0);
        }
        __syncthreads();

        s16x8 af[4], bf[4];
#pragma unroll
        for (int bm = 0; bm < 4; ++bm) {
            const int ml  = wm + bm * 16 + row16;
            const int pos = quad ^ ((ml >> 1) & 3);
            af[bm] = *(const s16x8*)&As[ml * 32 + pos * 8];
        }
#pragma unroll
        for (int bn = 0; bn < 4; ++bn) {
            const int nl  = wn + bn * 16 + row16;
            const int pos = quad ^ ((nl >> 1) & 3);
            bf[bn] = *(const s16x8*)&Bs[nl * 32 + pos * 8];
        }
#pragma unroll
        for (int bm = 0; bm < 4; ++bm)
#pragma unroll
            for (int bn = 0; bn < 4; ++bn)
                acc[bm][bn] = __builtin_amdgcn_mfma_f32_16x16x32_bf16(af[bm], bf[bn], acc[bm][bn], 0, 0, 0);
    }

#pragma unroll
    for (int bm = 0; bm < 4; ++bm) {
#pragma unroll
        for (int bn = 0; bn < 4; ++bn) {
            const int i_loc = wn + bn * 16 + row16;
#pragma unroll
            for (int r = 0; r < 4; ++r) {
                const int t_loc = wm + bm * 16 + quad * 4 + r;
                Obb[qkbase + (size_t)t_loc * Dm + i_loc] = f2b_rne(acc[bm][bn][r]);
            }
        }
    }
}

// ---------------------------------------------------------------------------
extern "C" void kernel_launch(void* const* d_in, const int* in_sizes, int n_in,
                              void* d_out, int out_size, void* d_ws, size_t ws_size,
                              hipStream_t stream)
{
    const float* x    = (const float*)d_in[0];
    const float* Wq   = (const float*)d_in[1];
    const float* Wk   = (const float*)d_in[2];
    const float* Wv   = (const float*)d_in[3];
    const float* Wo   = (const float*)d_in[4];
    const float* Wlr  = (const float*)d_in[5];
    const float* b_lr = (const float*)d_in[6];

    float* ws = (float*)d_ws;
    const size_t S  = (size_t)Mrows * Dm;    // 8388608
    const size_t SW = (size_t)Dm * Dm;       // 1048576
    float* Kb  = ws;
    float* Vb  = ws + S;
    float* LRb = ws + 2 * S;
    unsigned short* xb   = (unsigned short*)(ws + 3 * S);  // S bf16
    unsigned short* Wcp  = xb;                             // alias: xb dead before solve
    unsigned short* Q16  = xb + S;
    unsigned short* K16  = Q16 + S;
    unsigned short* Ut   = K16 + S;
    unsigned short* Obb  = Ut + S;
    unsigned short* Wqb  = Obb + S;
    unsigned short* Wkb  = Wqb + SW;
    unsigned short* Wvb  = Wkb + SW;
    unsigned short* Wlrb = Wvb + SW;
    unsigned short* Wob  = Wlrb + SW;
    // lifetime-disjoint aliases:
    unsigned short* K16lo = Ut;              // l2norm -> gram window
    float*          Gf    = (float*)Obb;     // gram -> solve window
    unsigned short* KThi  = (unsigned short*)Kb;  // gram -> solve window
    unsigned short* KTlo  = KThi + S;

    static int attr_done = 0;
    if (!attr_done) {
        (void)hipFuncSetAttribute((const void*)solve_coef,
                                  hipFuncAttributeMaxDynamicSharedMemorySize, 147456);
        attr_done = 1;
    }

    cvt_f32_bf16<<<S / 1024, 256, 0, stream>>>(x, xb);
    cvt_f32_bf16<<<SW / 1024, 256, 0, stream>>>(Wq, Wqb);
    cvt_f32_bf16<<<SW / 1024, 256, 0, stream>>>(Wk, Wkb);
    cvt_f32_bf16<<<SW / 1024, 256, 0, stream>>>(Wv, Wvb);
    cvt_f32_bf16<<<SW / 1024, 256, 0, stream>>>(Wlr, Wlrb);
    cvt_f32_bf16<<<SW / 1024, 256, 0, stream>>>(Wo, Wob);

    dim3 gg(Dm / 128, Mrows / 128);
    gemm_bf16<<<gg, 256, 0, stream>>>(xb, Wqb, nullptr, nullptr, Q16, 2);
    gemm_bf16<<<gg, 256, 0, stream>>>(xb, Wkb, nullptr, Kb, nullptr, 0);
    gemm_bf16<<<gg, 256, 0, stream>>>(xb, Wvb, nullptr, Vb, nullptr, 0);
    gemm_bf16<<<gg, 256, 0, stream>>>(xb, Wlrb, b_lr, LRb, nullptr, 1);

    l2norm_rows<<<(Bsz * Tlen * Hh) / 4, 256, 0, stream>>>(Kb, Vb, K16, K16lo);

    gram_kt<<<32 * 32, 256, 0, stream>>>(K16, K16lo, Gf, KThi, KTlo);

    solve_coef<<<32, 512, 147456, stream>>>(K16, Vb, LRb, Gf, KThi, KTlo, Ut, Wcp);

    chunk_o<<<Bsz * Hh * NCH, 256, 0, stream>>>(Q16, K16, Ut, Wcp, Obb);

    gemm_bf16<<<gg, 256, 0, stream>>>(Obb, Wob, nullptr, (float*)d_out, nullptr, 0);
}

// Round 10
// 890.146 us; speedup vs baseline: 1.3213x; 1.3213x over previous
//
#include <hip/hip_runtime.h>
#include <math.h>

#define Bsz  4
#define Tlen 2048
#define Dm   1024
#define Hh   8
#define dh   128
#define Mrows (Bsz * Tlen)   // 8192
#define CH   128             // checkpoint interval for pass 2
#define NCH  (Tlen / CH)     // 16 checkpoint chunks
#define C32  32              // solve chunk (R10: halved from 64 -> r4[8] = 32 VGPR, no spill)
#define NC32 (Tlen / C32)    // 64 solve chunks

typedef __attribute__((ext_vector_type(8))) short  s16x8;
typedef __attribute__((ext_vector_type(4))) float  f32x4;

__device__ inline unsigned short f2b_rne(float f) {
    unsigned int u = __float_as_uint(f);
    u += 0x7FFFu + ((u >> 16) & 1u);
    return (unsigned short)(u >> 16);
}
__device__ inline float b2f(unsigned short u) {
    return __uint_as_float(((unsigned int)u) << 16);
}

__global__ __launch_bounds__(256) void cvt_f32_bf16(const float* __restrict__ in,
                                                    unsigned short* __restrict__ out)
{
    const size_t i = ((size_t)blockIdx.x * 256 + threadIdx.x) * 4;
    float4 v = *(const float4*)&in[i];
    ushort4 o;
    o.x = f2b_rne(v.x); o.y = f2b_rne(v.y);
    o.z = f2b_rne(v.z); o.w = f2b_rne(v.w);
    *(ushort4*)&out[i] = o;
}

// ---------------------------------------------------------------------------
// bf16 MFMA GEMM: val = sum_k A[m][k]*W[n][k] (+bias)   (unchanged, proven)
// ---------------------------------------------------------------------------
__global__ __launch_bounds__(256) void gemm_bf16(const unsigned short* __restrict__ A,
                                                 const unsigned short* __restrict__ Wt,
                                                 const float* __restrict__ bias,
                                                 float* __restrict__ Yf,
                                                 unsigned short* __restrict__ Y16,
                                                 int mode)
{
    __shared__ __align__(16) unsigned short As[128 * 32];
    __shared__ __align__(16) unsigned short Bs[128 * 32];

    const int tid   = threadIdx.x;
    const int w     = tid >> 6;
    const int lane  = tid & 63;
    const int r4    = lane >> 2;
    const int p4    = lane & 3;
    const int row16 = lane & 15;
    const int quad  = lane >> 4;

    const int m0 = blockIdx.y * 128;
    const int n0 = blockIdx.x * 128;
    const int wm = (w >> 1) * 64;
    const int wn = (w & 1) * 64;

    f32x4 acc[4][4];
#pragma unroll
    for (int i = 0; i < 4; ++i)
#pragma unroll
        for (int j = 0; j < 4; ++j)
            acc[i][j] = (f32x4){0.f, 0.f, 0.f, 0.f};

    for (int k0 = 0; k0 < 1024; k0 += 32) {
        __syncthreads();
#pragma unroll
        for (int c = 0; c < 2; ++c) {
            const int ml  = w * 32 + c * 16 + r4;
            const int swz = (ml >> 1) & 3;
            const unsigned short* ga = A  + (size_t)(m0 + ml) * 1024 + k0 + ((p4 ^ swz) << 3);
            const unsigned short* gb = Wt + (size_t)(n0 + ml) * 1024 + k0 + ((p4 ^ swz) << 3);
            __builtin_amdgcn_global_load_lds(
                (const __attribute__((address_space(1))) void*)ga,
                (__attribute__((address_space(3))) void*)&As[(w * 32 + c * 16) * 32], 16, 0, 0);
            __builtin_amdgcn_global_load_lds(
                (const __attribute__((address_space(1))) void*)gb,
                (__attribute__((address_space(3))) void*)&Bs[(w * 32 + c * 16) * 32], 16, 0, 0);
        }
        __syncthreads();

        s16x8 af[4], bf[4];
#pragma unroll
        for (int bm = 0; bm < 4; ++bm) {
            const int ml  = wm + bm * 16 + row16;
            const int pos = quad ^ ((ml >> 1) & 3);
            af[bm] = *(const s16x8*)&As[ml * 32 + pos * 8];
        }
#pragma unroll
        for (int bn = 0; bn < 4; ++bn) {
            const int nl  = wn + bn * 16 + row16;
            const int pos = quad ^ ((nl >> 1) & 3);
            bf[bn] = *(const s16x8*)&Bs[nl * 32 + pos * 8];
        }
#pragma unroll
        for (int bm = 0; bm < 4; ++bm)
#pragma unroll
            for (int bn = 0; bn < 4; ++bn)
                acc[bm][bn] = __builtin_amdgcn_mfma_f32_16x16x32_bf16(af[bm], bf[bn], acc[bm][bn], 0, 0, 0);
    }

#pragma unroll
    for (int bm = 0; bm < 4; ++bm) {
        const int row = m0 + wm + bm * 16 + quad * 4;
#pragma unroll
        for (int bn = 0; bn < 4; ++bn) {
            const int col = n0 + wn + bn * 16 + row16;
            const float bb = bias ? bias[col] : 0.f;
#pragma unroll
            for (int r = 0; r < 4; ++r) {
                float val = acc[bm][bn][r] + bb;
                if (mode == 1) val = 1.f / (1.f + __expf(-val));
                if (mode == 2) Y16[(size_t)(row + r) * 1024 + col] = f2b_rne(val);
                else           Yf [(size_t)(row + r) * 1024 + col] = val;
            }
        }
    }
}

// ---------------------------------------------------------------------------
// L2-normalize K,V rows in place; write normalized K as bf16 (K16) and the
// bf16 residual (K16lo) for precision-compensated Grams.
// ---------------------------------------------------------------------------
__global__ __launch_bounds__(256) void l2norm_rows(float* __restrict__ Kb,
                                                   float* __restrict__ Vb,
                                                   unsigned short* __restrict__ K16,
                                                   unsigned short* __restrict__ K16lo)
{
    const int gtid = blockIdx.x * 256 + threadIdx.x;
    const int row  = gtid >> 6;
    const int lane = threadIdx.x & 63;
    const size_t base = (size_t)row * dh + lane * 2;

    float2 k2 = *(float2*)&Kb[base];
    float2 v2 = *(float2*)&Vb[base];
    float sk = k2.x * k2.x + k2.y * k2.y;
    float sv = v2.x * v2.x + v2.y * v2.y;
#pragma unroll
    for (int off = 1; off < 64; off <<= 1) {
        sk += __shfl_xor(sk, off);
        sv += __shfl_xor(sv, off);
    }
    const float rk = 1.f / fmaxf(sqrtf(sk), 1e-12f);
    const float rv = 1.f / fmaxf(sqrtf(sv), 1e-12f);
    k2.x *= rk; k2.y *= rk;
    v2.x *= rv; v2.y *= rv;
    *(float2*)&Kb[base] = k2;
    *(float2*)&Vb[base] = v2;
    const unsigned short hx = f2b_rne(k2.x), hy = f2b_rne(k2.y);
    ((unsigned int*)K16)[base >> 1] = (unsigned int)hx | ((unsigned int)hy << 16);
    const unsigned short lx = f2b_rne(k2.x - b2f(hx));
    const unsigned short ly = f2b_rne(k2.y - b2f(hy));
    ((unsigned int*)K16lo)[base >> 1] = (unsigned int)lx | ((unsigned int)ly << 16);
}

// ---------------------------------------------------------------------------
// gram_kt (C=32): per (bh, chunk): G = K_c K_c^T (32x32 f32, lo-compensated,
// MFMA) and K^T tiles [128 j][32 t] (bf16 hi/lo).
// Grid: 32*64 = 2048 blocks, 256 threads. Fully parallel.
// ---------------------------------------------------------------------------
__global__ __launch_bounds__(256) void gram_kt(const unsigned short* __restrict__ K16,
                                               const unsigned short* __restrict__ K16lo,
                                               float* __restrict__ Gf,
                                               unsigned short* __restrict__ KThi,
                                               unsigned short* __restrict__ KTlo)
{
    __shared__ __align__(16) unsigned short Kp[2][32 * 136];   // [hi/lo][t][j] pad-136

    const int blk = blockIdx.x;
    const int c   = blk & 63;
    const int bh  = blk >> 6;
    const int b   = bh >> 3, h = bh & 7;
    const int tid = threadIdx.x;

    // stage K rows (32 rows, 8 threads/row x 16 shorts)
    {
        const int row = tid >> 3, seg = (tid & 7) * 16;
        const size_t gsrc = ((size_t)(b * Tlen + c * C32 + row)) * Dm + h * dh + seg;
        const s16x8* ph = (const s16x8*)&K16[gsrc];
        const s16x8* pl = (const s16x8*)&K16lo[gsrc];
#pragma unroll
        for (int q = 0; q < 2; ++q) {
            *(s16x8*)&Kp[0][row * 136 + seg + q * 8] = ph[q];
            *(s16x8*)&Kp[1][row * 136 + seg + q * 8] = pl[q];
        }
    }
    __syncthreads();

    const int w     = tid >> 6;
    const int lane  = tid & 63;
    const int row16 = lane & 15;
    const int quad  = lane >> 4;
    const int sh = (w >> 1) * 16;
    const int th = (w & 1) * 16;

    f32x4 ag = (f32x4){0.f, 0.f, 0.f, 0.f};

    // 3 passes: hi*hi + hi*lo + lo*hi
#pragma unroll
    for (int pass = 0; pass < 3; ++pass) {
        const int pa = (pass == 2) ? 1 : 0;
        const int pb = (pass == 1) ? 1 : 0;
#pragma unroll
        for (int k0 = 0; k0 < 128; k0 += 32) {
            s16x8 af = *(const s16x8*)&Kp[pa][(sh + row16) * 136 + k0 + quad * 8];
            s16x8 bf = *(const s16x8*)&Kp[pb][(th + row16) * 136 + k0 + quad * 8];
            ag = __builtin_amdgcn_mfma_f32_16x16x32_bf16(af, bf, ag, 0, 0, 0);
        }
    }

    // write G f32 [bh][c][s][t]
    float* gout = Gf + ((size_t)(bh * 64 + c)) * 1024;
    {
        const int t = th + row16;
#pragma unroll
        for (int r = 0; r < 4; ++r) {
            const int s = sh + quad * 4 + r;
            gout[s * 32 + t] = ag[r];
        }
    }

    // K^T extraction: KT[bh][c][j][t]  (j=128, t=32)
    {
        const int j   = tid >> 1;
        const int th2 = (tid & 1) * 16;
        unsigned int pk[8];
#pragma unroll
        for (int hl = 0; hl < 2; ++hl) {
#pragma unroll
            for (int p = 0; p < 8; ++p) {
                const unsigned short e0 = Kp[hl][(th2 + 2 * p) * 136 + j];
                const unsigned short e1 = Kp[hl][(th2 + 2 * p + 1) * 136 + j];
                pk[p] = (unsigned int)e0 | ((unsigned int)e1 << 16);
            }
            unsigned short* dst = (hl ? KTlo : KThi) +
                ((size_t)(bh * 64 + c) * 128 + j) * 32 + th2;
#pragma unroll
            for (int q = 0; q < 2; ++q)
                *(uint4*)&dst[q * 8] = *(uint4*)&pk[q * 4];
        }
    }
}

// ---------------------------------------------------------------------------
// solve_coef R10 (C=32): 512 threads (8 waves), 4 barriers/chunk, K/G
// double-buffer prefetch, A0 in own buffer, Wcp direct-from-registers.
// r4[8] = 32 VGPR -> solver live set ~100 regs, fits the 128-reg allocation
// the compiler picks with dynamic LDS (R8/R9: r4[16]=64 spilled to scratch).
// Waves 0,1: solve (128 rows).  Waves 2,3: KT stage.  Waves 4,6: G prefetch.
// Wave 5: K prefetch.  Dynamic LDS: 80 KiB.
// ---------------------------------------------------------------------------
__global__ __launch_bounds__(512, 2) void solve_coef(const unsigned short* __restrict__ K16,
                                                     const float* __restrict__ Vb,
                                                     const float* __restrict__ LRb,
                                                     const float* __restrict__ Gf,
                                                     const unsigned short* __restrict__ KThi,
                                                     const unsigned short* __restrict__ KTlo,
                                                     unsigned short* __restrict__ Ut,
                                                     unsigned short* __restrict__ Wcp)
{
    extern __shared__ __align__(16) char smem[];
    unsigned short* Khs[2];                                    // 2 x 8K K staging [4 sl][32 t][32 j]
    Khs[0] = (unsigned short*)smem;
    Khs[1] = (unsigned short*)(smem + 8192);
    unsigned short* Ws  = (unsigned short*)(smem + 16384);     // 32K: P0/P1 W slabs; P2/P3 KT bufs (16K)
    float* Gs[2];                                              // 2 x 4K [32][32] f32
    Gs[0] = (float*)(smem + 49152);
    Gs[1] = (float*)(smem + 53248);
    unsigned short* As0 = (unsigned short*)(smem + 57344);     // 8K A0 [32 t][128 i] XOR
    unsigned short* Uhi = (unsigned short*)(smem + 65536);     // 8K [128][32] XOR
    unsigned short* Ulo = (unsigned short*)(smem + 73728);     // 8K [128][32] XOR

    const int bh = blockIdx.x;
    const int b  = bh >> 3, h = bh & 7;
    const int tid   = threadIdx.x;
    const int w     = tid >> 6;           // 0..7
    const int lane  = tid & 63;
    const int p4    = lane & 3;
    const int row16 = lane & 15;
    const int quad  = lane >> 4;
    const int wm  = (w >> 1) * 32;        // W/A0 i-quarter (0,32,64,96)
    const int wn  = (w & 1) * 64;         // W j-half
    const int th2 = (w & 1) * 16;         // A0 t-half (of 32)

    f32x4 Wa[2][4];
#pragma unroll
    for (int i = 0; i < 2; ++i)
#pragma unroll
        for (int j = 0; j < 4; ++j)
            Wa[i][j] = (f32x4){0.f, 0.f, 0.f, 0.f};

    const int ilane = w * 64 + lane;      // solve row (waves 0,1)

    // ---- prologue: stage K(0) -> Khs[0], G(0) -> Gs[0] ----
    if (w == 5) {
#pragma unroll
        for (int c4 = 0; c4 < 8; ++c4) {
            const int sl = c4 >> 1, e = c4 & 1;
            const int rr = e * 16 + (lane >> 2);
            const unsigned short* ga = K16 + ((size_t)(b * Tlen + rr)) * Dm + h * dh
                                       + sl * 32 + ((p4 ^ ((rr >> 1) & 3)) << 3);
            __builtin_amdgcn_global_load_lds(
                (const __attribute__((address_space(1))) void*)ga,
                (__attribute__((address_space(3))) void*)((char*)Khs[0] + sl * 2048 + e * 1024 + lane * 16),
                16, 0, 0);
        }
    }
    if (w == 4 || w == 6) {
        const size_t gbase = (size_t)(bh * 64 + 0) * 1024;
        const int half = (w == 6) ? 1 : 0;
#pragma unroll
        for (int e = 0; e < 2; ++e) {
            const float* gg = Gf + gbase + half * 512 + e * 256 + lane * 4;
            __builtin_amdgcn_global_load_lds(
                (const __attribute__((address_space(1))) void*)gg,
                (__attribute__((address_space(3))) void*)((char*)Gs[0] + (half * 512 + e * 256 + lane * 4) * 4),
                16, 0, 0);
        }
    }
    __syncthreads();

#pragma unroll 1
    for (int c = 0; c < NC32; ++c) {
        const int t0g = c * C32;
        const int cur = c & 1;

        // ---- P0: dump W -> Ws (bf16); Wcp direct store every 4th chunk --
#pragma unroll
        for (int bm = 0; bm < 2; ++bm)
#pragma unroll
            for (int bn = 0; bn < 4; ++bn) {
                const int j  = wn + bn * 16 + row16;
                const int sl = j >> 5, jj = j & 31;
#pragma unroll
                for (int r = 0; r < 4; ++r) {
                    const int i = wm + bm * 16 + quad * 4 + r;
                    const unsigned short hv = f2b_rne(Wa[bm][bn][r]);
                    Ws[sl * 4096 + i * 32 + (((jj >> 3) ^ ((i >> 1) & 3)) << 3) + (j & 7)] = hv;
                    if ((c & 3) == 0)
                        Wcp[((size_t)(bh * NCH + (c >> 2)) * 128 + i) * 128 + j] = hv;
                }
            }
        __syncthreads();

        // ---- P1: A0 = W * K_c^T (MFMA, 8 waves) -> As0 ------------------
        {
            f32x4 aA[2];
#pragma unroll
            for (int i = 0; i < 2; ++i)
                aA[i] = (f32x4){0.f, 0.f, 0.f, 0.f};
#pragma unroll
            for (int k0s = 0; k0s < 4; ++k0s) {
                const int nl = th2 + row16;
                s16x8 bf = *(const s16x8*)&Khs[cur][k0s * 1024 + nl * 32 + ((quad ^ ((nl >> 1) & 3)) << 3)];
#pragma unroll
                for (int bm = 0; bm < 2; ++bm) {
                    const int ml = wm + bm * 16 + row16;
                    s16x8 af = *(const s16x8*)&Ws[k0s * 4096 + ml * 32 + ((quad ^ ((ml >> 1) & 3)) << 3)];
                    aA[bm] = __builtin_amdgcn_mfma_f32_16x16x32_bf16(af, bf, aA[bm], 0, 0, 0);
                }
            }
#pragma unroll
            for (int bm = 0; bm < 2; ++bm) {
                const int t = th2 + row16;
#pragma unroll
                for (int r = 0; r < 4; ++r) {
                    const int i = wm + bm * 16 + quad * 4 + r;
                    As0[t * 128 + (((i >> 3) ^ (t & 7)) << 3) + (i & 7)] = f2b_rne(aA[bm][r]);
                }
            }
        }
        __syncthreads();

        // ---- P2: waves 0,1 solve; 2,3 KT stage; 4,6 G-next; 5 K-next ----
        if (w == 2 || w == 3) {
            const int buf = w - 2;                  // 0: hi, 1: lo
            const unsigned short* src = (buf == 0) ? KThi : KTlo;
#pragma unroll
            for (int e = 0; e < 8; ++e) {
                const int jj = e * 16 + (lane >> 2);
                const unsigned short* ga = src + ((size_t)(bh * 64 + c) * 128 + jj) * 32
                                           + ((p4 ^ ((jj >> 1) & 3)) << 3);
                __builtin_amdgcn_global_load_lds(
                    (const __attribute__((address_space(1))) void*)ga,
                    (__attribute__((address_space(3))) void*)((char*)Ws + buf * 8192 + e * 1024 + lane * 16),
                    16, 0, 0);
            }
        } else if (w == 5) {
            if (c + 1 < NC32) {
#pragma unroll
                for (int c4 = 0; c4 < 8; ++c4) {
                    const int sl = c4 >> 1, e = c4 & 1;
                    const int rr = e * 16 + (lane >> 2);
                    const unsigned short* ga = K16 + ((size_t)(b * Tlen + t0g + C32 + rr)) * Dm + h * dh
                                               + sl * 32 + ((p4 ^ ((rr >> 1) & 3)) << 3);
                    __builtin_amdgcn_global_load_lds(
                        (const __attribute__((address_space(1))) void*)ga,
                        (__attribute__((address_space(3))) void*)((char*)Khs[cur ^ 1] + sl * 2048 + e * 1024 + lane * 16),
                        16, 0, 0);
                }
            }
        } else if (w == 4 || w == 6) {
            if (c + 1 < NC32) {
                const size_t gbase = (size_t)(bh * 64 + c + 1) * 1024;
                const int half = (w == 6) ? 1 : 0;
#pragma unroll
                for (int e = 0; e < 2; ++e) {
                    const float* gg = Gf + gbase + half * 512 + e * 256 + lane * 4;
                    __builtin_amdgcn_global_load_lds(
                        (const __attribute__((address_space(1))) void*)gg,
                        (__attribute__((address_space(3))) void*)((char*)Gs[cur ^ 1] + (half * 512 + e * 256 + lane * 4) * 4),
                        16, 0, 0);
                }
            }
        } else if (w < 2) {
            const int i = ilane;
            const float* vp  = Vb  + ((size_t)(b * Tlen + t0g)) * Dm + h * dh + i;
            const float* lrp = LRb + ((size_t)(b * Tlen + t0g)) * Dm + h * dh + i;
            const float* gs  = Gs[cur];
            unsigned short* utrow = Ut + (size_t)(bh * 128 + i) * Tlen + t0g;
            // r-init: r4[q][e] = v[t] - A0[t][i],  t = 4q+e  (q<8, t<32)
            f32x4 r4[8];
#pragma unroll
            for (int q = 0; q < 8; ++q) {
#pragma unroll
                for (int e = 0; e < 4; ++e) {
                    const int t = 4 * q + e;
                    const float a0 = b2f(As0[t * 128 + (((i >> 3) ^ (t & 7)) << 3) + (i & 7)]);
                    r4[q][e] = vp[(size_t)t * Dm] - a0;
                }
            }
            float lv[8], o8[8];
#pragma unroll
            for (int g = 0; g < 4; ++g) {
#pragma unroll
                for (int u = 0; u < 8; ++u)
                    lv[u] = lrp[(size_t)(g * 8 + u) * Dm];
#pragma unroll
                for (int su = 0; su < 8; ++su) {
                    const int s = g * 8 + su;
                    const float cf = lv[su] * r4[s >> 2][s & 3];   // static idx (unrolled)
                    o8[su] = cf;
                    const f32x4 cf4 = (f32x4){cf, cf, cf, cf};
                    // compile-time trip: quads 2g..7 (earlier quads consumed/dead)
#pragma unroll
                    for (int q = 2 * g; q < 8; ++q) {
                        const f32x4 g4 = *(const f32x4*)&gs[s * 32 + q * 4];
                        r4[q] -= cf4 * g4;
                    }
                }
                // pack & store U for this group (t0 = 8g)
                unsigned int phi[4], plo[4];
#pragma unroll
                for (int qq = 0; qq < 4; ++qq) {
                    const unsigned short h0 = f2b_rne(o8[2 * qq]);
                    const unsigned short h1 = f2b_rne(o8[2 * qq + 1]);
                    const unsigned short l0 = f2b_rne(o8[2 * qq] - b2f(h0));
                    const unsigned short l1 = f2b_rne(o8[2 * qq + 1] - b2f(h1));
                    phi[qq] = (unsigned int)h0 | ((unsigned int)h1 << 16);
                    plo[qq] = (unsigned int)l0 | ((unsigned int)l1 << 16);
                }
                const int lg = g ^ (i & 3);
                *(uint4*)&Uhi[i * 32 + (lg << 3)] = *(uint4*)phi;
                *(uint4*)&Ulo[i * 32 + (lg << 3)] = *(uint4*)plo;
                *(uint4*)&utrow[8 * g] = *(uint4*)phi;
            }
        }
        __syncthreads();

        // ---- P3: W += Uhi*KThi + Ulo*KThi + Uhi*KTlo (MFMA, 8 waves) ----
#pragma unroll
        for (int pass = 0; pass < 3; ++pass) {
            const unsigned short* Ua = (pass == 1) ? Ulo : Uhi;
            const int buf = (pass == 2) ? 1 : 0;
            s16x8 af[2], bf[4];
#pragma unroll
            for (int bm = 0; bm < 2; ++bm) {
                const int ml = wm + bm * 16 + row16;
                af[bm] = *(const s16x8*)&Ua[ml * 32 + ((quad ^ (ml & 3)) << 3)];
            }
#pragma unroll
            for (int bn = 0; bn < 4; ++bn) {
                const int nl = wn + bn * 16 + row16;
                bf[bn] = *(const s16x8*)&Ws[buf * 4096 + nl * 32 + ((quad ^ ((nl >> 1) & 3)) << 3)];
            }
#pragma unroll
            for (int bm = 0; bm < 2; ++bm)
#pragma unroll
                for (int bn = 0; bn < 4; ++bn)
                    Wa[bm][bn] = __builtin_amdgcn_mfma_f32_16x16x32_bf16(af[bm], bf[bn], Wa[bm][bn], 0, 0, 0);
        }
        __syncthreads();
    }
}

// ---------------------------------------------------------------------------
// Pass 2: per 128-chunk output via MFMA.  (unchanged, proven)
// ---------------------------------------------------------------------------
__global__ __launch_bounds__(256) void chunk_o(const unsigned short* __restrict__ Q16,
                                               const unsigned short* __restrict__ K16,
                                               const unsigned short* __restrict__ Ut,
                                               const unsigned short* __restrict__ Wcp,
                                               unsigned short* __restrict__ Obb)
{
    __shared__ __align__(16) unsigned short As[128 * 32];
    __shared__ __align__(16) unsigned short Bs[128 * 32];
    __shared__ __align__(16) unsigned short Sb[128 * 136];   // +8 pad

    const int blk = blockIdx.x;
    const int c   = blk & (NCH - 1);
    const int bh  = blk >> 4;
    const int b   = bh >> 3, h = bh & 7;

    const int tid   = threadIdx.x;
    const int w     = tid >> 6;
    const int lane  = tid & 63;
    const int r4    = lane >> 2;
    const int p4    = lane & 3;
    const int row16 = lane & 15;
    const int quad  = lane >> 4;
    const int wm = (w >> 1) * 64;
    const int wn = (w & 1) * 64;

    const size_t qkbase = (size_t)b * Tlen * Dm + (size_t)(c * CH) * Dm + (size_t)h * dh;
    const size_t ubase  = (size_t)bh * dh * Tlen + (size_t)c * CH;
    const size_t wbase  = ((size_t)bh * NCH + c) * dh * dh;

    f32x4 acc[4][4];
#pragma unroll
    for (int i = 0; i < 4; ++i)
#pragma unroll
        for (int j = 0; j < 4; ++j)
            acc[i][j] = (f32x4){0.f, 0.f, 0.f, 0.f};

    for (int k0 = 0; k0 < 128; k0 += 32) {
        __syncthreads();
#pragma unroll
        for (int cc = 0; cc < 2; ++cc) {
            const int ml  = w * 32 + cc * 16 + r4;
            const int swz = (ml >> 1) & 3;
            const unsigned short* ga = Q16 + qkbase + (size_t)ml * Dm + k0 + ((p4 ^ swz) << 3);
            const unsigned short* gb = K16 + qkbase + (size_t)ml * Dm + k0 + ((p4 ^ swz) << 3);
            __builtin_amdgcn_global_load_lds(
                (const __attribute__((address_space(1))) void*)ga,
                (__attribute__((address_space(3))) void*)&As[(w * 32 + cc * 16) * 32], 16, 0, 0);
            __builtin_amdgcn_global_load_lds(
                (const __attribute__((address_space(1))) void*)gb,
                (__attribute__((address_space(3))) void*)&Bs[(w * 32 + cc * 16) * 32], 16, 0, 0);
        }
        __syncthreads();

        s16x8 af[4], bf[4];
#pragma unroll
        for (int bm = 0; bm < 4; ++bm) {
            const int ml  = wm + bm * 16 + row16;
            const int pos = quad ^ ((ml >> 1) & 3);
            af[bm] = *(const s16x8*)&As[ml * 32 + pos * 8];
        }
#pragma unroll
        for (int bn = 0; bn < 4; ++bn) {
            const int nl  = wn + bn * 16 + row16;
            const int pos = quad ^ ((nl >> 1) & 3);
            bf[bn] = *(const s16x8*)&Bs[nl * 32 + pos * 8];
        }
#pragma unroll
        for (int bm = 0; bm < 4; ++bm)
#pragma unroll
            for (int bn = 0; bn < 4; ++bn)
                acc[bm][bn] = __builtin_amdgcn_mfma_f32_16x16x32_bf16(af[bm], bf[bn], acc[bm][bn], 0, 0, 0);
    }

#pragma unroll
    for (int bm = 0; bm < 4; ++bm) {
#pragma unroll
        for (int bn = 0; bn < 4; ++bn) {
            const int s_loc = wn + bn * 16 + row16;
#pragma unroll
            for (int r = 0; r < 4; ++r) {
                const int t_loc = wm + bm * 16 + quad * 4 + r;
                const float val = (s_loc <= t_loc) ? acc[bm][bn][r] : 0.f;
                Sb[t_loc * 136 + s_loc] = f2b_rne(val);
            }
            acc[bm][bn] = (f32x4){0.f, 0.f, 0.f, 0.f};
        }
    }

    for (int k0 = 0; k0 < 128; k0 += 32) {
        __syncthreads();
#pragma unroll
        for (int cc = 0; cc < 2; ++cc) {
            const int nl  = w * 32 + cc * 16 + r4;
            const int swz = (nl >> 1) & 3;
            const unsigned short* gb = Ut + ubase + (size_t)nl * Tlen + k0 + ((p4 ^ swz) << 3);
            __builtin_amdgcn_global_load_lds(
                (const __attribute__((address_space(1))) void*)gb,
                (__attribute__((address_space(3))) void*)&Bs[(w * 32 + cc * 16) * 32], 16, 0, 0);
        }
        __syncthreads();

        s16x8 af[4], bf[4];
#pragma unroll
        for (int bm = 0; bm < 4; ++bm) {
            const int ml = wm + bm * 16 + row16;
            af[bm] = *(const s16x8*)&Sb[ml * 136 + k0 + quad * 8];
        }
#pragma unroll
        for (int bn = 0; bn < 4; ++bn) {
            const int nl  = wn + bn * 16 + row16;
            const int pos = quad ^ ((nl >> 1) & 3);
            bf[bn] = *(const s16x8*)&Bs[nl * 32 + pos * 8];
        }
#pragma unroll
        for (int bm = 0; bm < 4; ++bm)
#pragma unroll
            for (int bn = 0; bn < 4; ++bn)
                acc[bm][bn] = __builtin_amdgcn_mfma_f32_16x16x32_bf16(af[bm], bf[bn], acc[bm][bn], 0, 0, 0);
    }

    for (int k0 = 0; k0 < 128; k0 += 32) {
        __syncthreads();
#pragma unroll
        for (int cc = 0; cc < 2; ++cc) {
            const int ml  = w * 32 + cc * 16 + r4;
            const int swz = (ml >> 1) & 3;
            const unsigned short* ga = Q16 + qkbase + (size_t)ml * Dm + k0 + ((p4 ^ swz) << 3);
            const unsigned short* gb = Wcp + wbase + (size_t)ml * dh + k0 + ((p4 ^ swz) << 3);
            __builtin_amdgcn_global_load_lds(
                (const __attribute__((address_space(1))) void*)ga,
                (__attribute__((address_space(3))) void*)&As[(w * 32 + cc * 16) * 32], 16, 0, 0);
            __builtin_amdgcn_global_load_lds(
                (const __attribute__((address_space(1))) void*)gb,
                (__attribute__((address_space(3))) void*)&Bs[(w * 32 + cc * 16) * 32], 16, 0, 0);
        }
        __syncthreads();

        s16x8 af[4], bf[4];
#pragma unroll
        for (int bm = 0; bm < 4; ++bm) {
            const int ml  = wm + bm * 16 + row16;
            const int pos = quad ^ ((ml >> 1) & 3);
            af[bm] = *(const s16x8*)&As[ml * 32 + pos * 8];
        }
#pragma unroll
        for (int bn = 0; bn < 4; ++bn) {
            const int nl  = wn + bn * 16 + row16;
            const int pos = quad ^ ((nl >> 1) & 3);
            bf[bn] = *(const s16x8*)&Bs[nl * 32 + pos * 8];
        }
#pragma unroll
        for (int bm = 0; bm < 4; ++bm)
#pragma unroll
            for (int bn = 0; bn < 4; ++bn)
                acc[bm][bn] = __builtin_amdgcn_mfma_f32_16x16x32_bf16(af[bm], bf[bn], acc[bm][bn], 0, 0, 0);
    }

#pragma unroll
    for (int bm = 0; bm < 4; ++bm) {
#pragma unroll
        for (int bn = 0; bn < 4; ++bn) {
            const int i_loc = wn + bn * 16 + row16;
#pragma unroll
            for (int r = 0; r < 4; ++r) {
                const int t_loc = wm + bm * 16 + quad * 4 + r;
                Obb[qkbase + (size_t)t_loc * Dm + i_loc] = f2b_rne(acc[bm][bn][r]);
            }
        }
    }
}

// ---------------------------------------------------------------------------
extern "C" void kernel_launch(void* const* d_in, const int* in_sizes, int n_in,
                              void* d_out, int out_size, void* d_ws, size_t ws_size,
                              hipStream_t stream)
{
    const float* x    = (const float*)d_in[0];
    const float* Wq   = (const float*)d_in[1];
    const float* Wk   = (const float*)d_in[2];
    const float* Wv   = (const float*)d_in[3];
    const float* Wo   = (const float*)d_in[4];
    const float* Wlr  = (const float*)d_in[5];
    const float* b_lr = (const float*)d_in[6];

    float* ws = (float*)d_ws;
    const size_t S  = (size_t)Mrows * Dm;    // 8388608
    const size_t SW = (size_t)Dm * Dm;       // 1048576
    float* Kb  = ws;
    float* Vb  = ws + S;
    float* LRb = ws + 2 * S;
    unsigned short* xb   = (unsigned short*)(ws + 3 * S);  // S bf16
    unsigned short* Wcp  = xb;                             // alias: xb dead before solve
    unsigned short* Q16  = xb + S;
    unsigned short* K16  = Q16 + S;
    unsigned short* Ut   = K16 + S;
    unsigned short* Obb  = Ut + S;
    unsigned short* Wqb  = Obb + S;
    unsigned short* Wkb  = Wqb + SW;
    unsigned short* Wvb  = Wkb + SW;
    unsigned short* Wlrb = Wvb + SW;
    unsigned short* Wob  = Wlrb + SW;
    // lifetime-disjoint aliases:
    unsigned short* K16lo = Ut;              // l2norm -> gram window
    float*          Gf    = (float*)Obb;     // gram -> solve window (2M f32 = 8MB < |Obb|)
    unsigned short* KThi  = (unsigned short*)Kb;  // gram -> solve window (8M shorts)
    unsigned short* KTlo  = KThi + S;        // 8M shorts; hi+lo = |Kb| f32

    static int attr_done = 0;
    if (!attr_done) {
        (void)hipFuncSetAttribute((const void*)solve_coef,
                                  hipFuncAttributeMaxDynamicSharedMemorySize, 81920);
        attr_done = 1;
    }

    cvt_f32_bf16<<<S / 1024, 256, 0, stream>>>(x, xb);
    cvt_f32_bf16<<<SW / 1024, 256, 0, stream>>>(Wq, Wqb);
    cvt_f32_bf16<<<SW / 1024, 256, 0, stream>>>(Wk, Wkb);
    cvt_f32_bf16<<<SW / 1024, 256, 0, stream>>>(Wv, Wvb);
    cvt_f32_bf16<<<SW / 1024, 256, 0, stream>>>(Wlr, Wlrb);
    cvt_f32_bf16<<<SW / 1024, 256, 0, stream>>>(Wo, Wob);

    dim3 gg(Dm / 128, Mrows / 128);
    gemm_bf16<<<gg, 256, 0, stream>>>(xb, Wqb, nullptr, nullptr, Q16, 2);
    gemm_bf16<<<gg, 256, 0, stream>>>(xb, Wkb, nullptr, Kb, nullptr, 0);
    gemm_bf16<<<gg, 256, 0, stream>>>(xb, Wvb, nullptr, Vb, nullptr, 0);
    gemm_bf16<<<gg, 256, 0, stream>>>(xb, Wlrb, b_lr, LRb, nullptr, 1);

    l2norm_rows<<<(Bsz * Tlen * Hh) / 4, 256, 0, stream>>>(Kb, Vb, K16, K16lo);

    gram_kt<<<32 * 64, 256, 0, stream>>>(K16, K16lo, Gf, KThi, KTlo);

    solve_coef<<<32, 512, 81920, stream>>>(K16, Vb, LRb, Gf, KThi, KTlo, Ut, Wcp);

    chunk_o<<<Bsz * Hh * NCH, 256, 0, stream>>>(Q16, K16, Ut, Wcp, Obb);

    gemm_bf16<<<gg, 256, 0, stream>>>(Obb, Wob, nullptr, (float*)d_out, nullptr, 0);
}